// Round 16
// baseline (5974.500 us; speedup 1.0000x reference)
//
#include <hip/hip_runtime.h>

// ---------------------------------------------------------------------------
// BiGRU encoder, MI355X. Round 16 = round 11 (proven, 5.53 ms) with the
// PUBLISH TAIL MOVED OFF THE CRITICAL WAVE: wave A computes gates and hands
// h2 to wave B (LDS slot ring, r9-proven); wave B does pack -> h store ->
// vmcnt drain -> replica flags -> out[], plus gi (computed 4 steps ahead;
// prelude fills the fifo). A starts polling step t+1 immediately after the
// handoff -> step period becomes max(publish-tail, compute-head), not sum.
//
// 64 blocks, 128 threads (2 waves), 1 block/CU.
//   wave A: poll -> af load -> 48 MFMA gh -> gates -> fout handoff.
//   wave B: fout -> pack -> h store(sc0sc1) -> drain -> flags -> out[];
//           gi(t+4) -> fifo.
//
// ws layout:
//   Xb   [T][B][F] bf16      33,554,432 B
//   Hf   [T][B][F] bf16      33,554,432 B
//   Hb   [T][B][F] bf16      33,554,432 B
//   Wb   [2][2][1536][512]    6,291,456 B   (dir, src{0=Whh,1=Wih})
//   flags 2 dirs x 4 replicas x 32 int
// ---------------------------------------------------------------------------

#define TT 2048
#define BB 16
#define FF 512
#define LL 10
#define RD 4
#define NTHR 128

typedef __attribute__((ext_vector_type(8))) short short8;
typedef __attribute__((ext_vector_type(4))) int   int4v;
typedef __attribute__((ext_vector_type(2))) int   int2v;
typedef __attribute__((ext_vector_type(4))) float f32x4;

// D = A*B + C with A (weights) pinned to AGPR, B (activations) in VGPR.
#define MFMA_WA(acc, wfa, afb) \
  asm("v_mfma_f32_16x16x32_bf16 %0, %1, %2, %0" : "+v"(acc) : "a"(wfa), "v"(afb))

__device__ __forceinline__ unsigned short f2bf(float f) {
  union { float f; unsigned int u; } v; v.f = f;
  unsigned int u = v.u;
  return (unsigned short)((u + 0x7fffu + ((u >> 16) & 1u)) >> 16);
}
__device__ __forceinline__ float bf2f(unsigned short h) {
  union { unsigned int u; float f; } v; v.u = ((unsigned int)h) << 16;
  return v.f;
}

__global__ void prep_x(const float* __restrict__ x, unsigned short* __restrict__ Xb) {
  int i = blockIdx.x * blockDim.x + threadIdx.x;
  int f = i & (FF - 1);
  int b = (i >> 9) & (BB - 1);
  int t = i >> 13;
  Xb[i] = f2bf(x[(size_t)b * (TT * 1025) + t * 1025 + f]);
}

__global__ void prep_w(const float* __restrict__ a, const float* __restrict__ b,
                       const float* __restrict__ c, const float* __restrict__ d,
                       unsigned short* __restrict__ Wb) {
  const int M = 1536 * 512;
  int i = blockIdx.x * blockDim.x + threadIdx.x;
  int m = i / M, r = i - m * M;
  const float* src = (m == 0) ? a : (m == 1) ? b : (m == 2) ? c : d;
  Wb[i] = f2bf(src[r]);
}

__global__ void prep_flags(int* __restrict__ flags) {
  int i = threadIdx.x;
  if (i < 256) flags[i] = 0;
}

// ---------------------------------------------------------------------------
__global__ void __launch_bounds__(NTHR, 1) bigru_rec(
    const unsigned short* __restrict__ Xb,
    unsigned short* __restrict__ Hf, unsigned short* __restrict__ Hb,
    const unsigned short* __restrict__ Wb,
    const float* __restrict__ bih_f, const float* __restrict__ bhh_f,
    const float* __restrict__ bih_b, const float* __restrict__ bhh_b,
    int* __restrict__ flags, float* __restrict__ out)
{
  const int bid  = blockIdx.x;
  const int d    = bid >> 5;           // direction
  const int j    = bid & 31;           // slice (16 hidden cols)
  const int tid  = threadIdx.x;
  const int w    = tid >> 6;           // 0 = gh/gates wave, 1 = publish/gi wave
  const int lane = tid & 63;
  const int l15  = lane & 15;          // batch row (D col, operand-swapped)
  const int hi   = lane >> 4;          // quarter: 4 adjacent out-cols
  const int lk   = hi * 8;
  const int cb   = j * 16 + hi * 4;    // this lane's first out-col

  unsigned short* Hst = d ? Hb : Hf;
  int* flg = flags + d * 128;          // 4 replica lines of 32 ints
  const float* bih = d ? bih_b : bih_f;
  const float* bhh = d ? bhh_b : bhh_f;

  __shared__ float fifo[RD][64][17];   // B -> A : gi gates + residual x
  __shared__ float fout[RD][64][5];    // A -> B : h2 values (publish handoff)
  __shared__ int wrote_s, consumed_s, outA_s, outdone_s;
  if (tid == 0) { wrote_s = 0; consumed_s = 0; outA_s = 0; outdone_s = 0; }
  __syncthreads();

  // Weights: plain loads; used only via "a" MFMA constraint -> homed in AGPRs.
  const int src = w;                   // 0=Whh, 1=Wih
  int4v wf[3][16];
#pragma unroll
  for (int g = 0; g < 3; ++g) {
    const unsigned short* wrow =
        Wb + (size_t)((d * 2 + src) * 1536 + g * 512 + j * 16 + l15) * 512 + lk;
#pragma unroll
    for (int kk = 0; kk < 16; ++kk)
      wf[g][kk] = *(const int4v*)(wrow + kk * 32);
  }

  if (w == 0) {
    // ============ WAVE A: poll -> gh MFMA -> gates -> handoff ==============
    __builtin_amdgcn_s_setprio(1);
    const f32x4 bh0 = *(const f32x4*)(bhh + cb);
    const f32x4 bh1 = *(const f32x4*)(bhh + 512 + cb);
    const f32x4 bh2 = *(const f32x4*)(bhh + 1024 + cb);
    float hc[4] = {0.f, 0.f, 0.f, 0.f};   // carry: batch l15, cols cb+jj
    int* myrep = flg + (j & 3) * 32;       // this consumer's flag replica line

    for (int t = 0; t < TT; ++t) {
      f32x4 a0 = {0,0,0,0}, a1 = {0,0,0,0}, a2 = {0,0,0,0},
            a3 = {0,0,0,0}, a4 = {0,0,0,0}, a5 = {0,0,0,0};
      if (t > 0) {
        int vv = t;
        for (;;) {
          if (lane < 32)
            vv = __hip_atomic_load(myrep + lane, __ATOMIC_RELAXED,
                                   __HIP_MEMORY_SCOPE_AGENT);
          if (__all(lane < 32 ? (vv >= t) : 1)) break;
        }
        __builtin_amdgcn_sched_barrier(0);   // no load hoisting above the poll
        const unsigned short* Arow =
            Hst + (size_t)((t - 1) * BB + l15) * FF + lk;
        int4v af[16];
#pragma unroll
        for (int kk = 0; kk < 16; ++kk)
          af[kk] = *(const int4v*)(Arow + kk * 32);
#pragma unroll
        for (int kk = 0; kk < 16; kk += 2) {
          MFMA_WA(a0, wf[0][kk],     af[kk]);
          MFMA_WA(a2, wf[1][kk],     af[kk]);
          MFMA_WA(a4, wf[2][kk],     af[kk]);
          MFMA_WA(a1, wf[0][kk + 1], af[kk + 1]);
          MFMA_WA(a3, wf[1][kk + 1], af[kk + 1]);
          MFMA_WA(a5, wf[2][kk + 1], af[kk + 1]);
        }
        asm volatile("s_nop 7\n\ts_nop 7");  // MFMA D -> VALU hazard guard
      }
      const int slot = t & (RD - 1);
      while (__hip_atomic_load(&wrote_s, __ATOMIC_ACQUIRE,
                               __HIP_MEMORY_SCOPE_WORKGROUP) < t + 1) {}
      float fr[4], fz[4], fn[4], fx[4];
#pragma unroll
      for (int jj = 0; jj < 4; ++jj) {
        fr[jj] = fifo[slot][lane][jj];
        fz[jj] = fifo[slot][lane][4 + jj];
        fn[jj] = fifo[slot][lane][8 + jj];
        fx[jj] = fifo[slot][lane][12 + jj];
      }
      __hip_atomic_store(&consumed_s, t + 1, __ATOMIC_RELEASE,
                         __HIP_MEMORY_SCOPE_WORKGROUP);

      f32x4 h2v;
#pragma unroll
      for (int jj = 0; jj < 4; ++jj) {
        const float ghr = a0[jj] + a1[jj] + bh0[jj];
        const float ghz = a2[jj] + a3[jj] + bh1[jj];
        const float ghn = a4[jj] + a5[jj] + bh2[jj];
        const float rr = 1.f / (1.f + __expf(-(fr[jj] + ghr)));
        const float zz = 1.f / (1.f + __expf(-(fz[jj] + ghz)));
        const float ee = __expf(2.f * (fn[jj] + rr * ghn));
        const float nn = 1.f - 2.f / (ee + 1.f);        // tanh, inf-safe
        const float h2 = (1.f - zz) * nn + zz * hc[jj] + fx[jj];
        hc[jj] = h2; h2v[jj] = h2;
      }
      // handoff to wave B (publish tail runs there); A proceeds to next poll
      while (__hip_atomic_load(&outdone_s, __ATOMIC_ACQUIRE,
                               __HIP_MEMORY_SCOPE_WORKGROUP) <= t - RD) {}
#pragma unroll
      for (int jj = 0; jj < 4; ++jj)
        fout[slot][lane][jj] = h2v[jj];
      __hip_atomic_store(&outA_s, t + 1, __ATOMIC_RELEASE,
                         __HIP_MEMORY_SCOPE_WORKGROUP);
    }
  } else {
    // ============ WAVE B: publish tail + gi (4 steps ahead) ================
    const f32x4 bi0 = *(const f32x4*)(bih + cb);
    const f32x4 bi1 = *(const f32x4*)(bih + 512 + cb);
    const f32x4 bi2 = *(const f32x4*)(bih + 1024 + cb);

    // prelude: gi for t = 0..RD-1 (no dependencies)
    for (int t = 0; t < RD; ++t) {
      const int tx = d ? (TT - 1 - t) : t;
      const unsigned short* Arow = Xb + (size_t)(tx * BB + l15) * FF + lk;
      int4v af[16];
#pragma unroll
      for (int kk = 0; kk < 16; ++kk)
        af[kk] = *(const int4v*)(Arow + kk * 32);
      f32x4 a0 = {0,0,0,0}, a1 = {0,0,0,0}, a2 = {0,0,0,0},
            a3 = {0,0,0,0}, a4 = {0,0,0,0}, a5 = {0,0,0,0};
#pragma unroll
      for (int kk = 0; kk < 16; kk += 2) {
        MFMA_WA(a0, wf[0][kk],     af[kk]);
        MFMA_WA(a2, wf[1][kk],     af[kk]);
        MFMA_WA(a4, wf[2][kk],     af[kk]);
        MFMA_WA(a1, wf[0][kk + 1], af[kk + 1]);
        MFMA_WA(a3, wf[1][kk + 1], af[kk + 1]);
        MFMA_WA(a5, wf[2][kk + 1], af[kk + 1]);
      }
      asm volatile("s_nop 7\n\ts_nop 7");
      const int2v xw = *(const int2v*)(Xb + (size_t)(tx * BB + l15) * FF + cb);
#pragma unroll
      for (int jj = 0; jj < 4; ++jj) {
        const unsigned int xu = (jj < 2) ? (unsigned int)xw[0] : (unsigned int)xw[1];
        fifo[t][lane][jj]      = a0[jj] + a1[jj] + bi0[jj];
        fifo[t][lane][4 + jj]  = a2[jj] + a3[jj] + bi1[jj];
        fifo[t][lane][8 + jj]  = a4[jj] + a5[jj] + bi2[jj];
        fifo[t][lane][12 + jj] = bf2f((unsigned short)((jj & 1) ? (xu >> 16) : (xu & 0xffff)));
      }
      __hip_atomic_store(&wrote_s, t + 1, __ATOMIC_RELEASE,
                         __HIP_MEMORY_SCOPE_WORKGROUP);
    }

    for (int t = 0; t < TT; ++t) {
      const int slot = t & (RD - 1);
      // wait for A's h2 handoff
      while (__hip_atomic_load(&outA_s, __ATOMIC_ACQUIRE,
                               __HIP_MEMORY_SCOPE_WORKGROUP) < t + 1) {}
      f32x4 h2v;
#pragma unroll
      for (int jj = 0; jj < 4; ++jj)
        h2v[jj] = fout[slot][lane][jj];
      __hip_atomic_store(&outdone_s, t + 1, __ATOMIC_RELEASE,
                         __HIP_MEMORY_SCOPE_WORKGROUP);
      // pack + h store (write-through) + drain + flags
      unsigned short us[4];
#pragma unroll
      for (int jj = 0; jj < 4; ++jj) us[jj] = f2bf(h2v[jj]);
      const unsigned int dw0 = (unsigned int)us[0] | ((unsigned int)us[1] << 16);
      const unsigned int dw1 = (unsigned int)us[2] | ((unsigned int)us[3] << 16);
      const unsigned int p0 = (unsigned int)__shfl_xor((int)dw0, 16);
      const unsigned int p1 = (unsigned int)__shfl_xor((int)dw1, 16);
      if (!(hi & 1)) {
        int4v pk; pk[0] = (int)dw0; pk[1] = (int)dw1;
        pk[2] = (int)p0; pk[3] = (int)p1;
        unsigned short* wp =
            Hst + (size_t)(t * BB + l15) * FF + j * 16 + (hi >> 1) * 8;
        asm volatile("global_store_dwordx4 %0, %1, off sc0 sc1"
                     :: "v"(wp), "v"(pk) : "memory");
      }
      asm volatile("s_waitcnt vmcnt(0)" ::: "memory");   // h at coherence point
      if (lane == 0) {                 // publish to all 4 replica lines
#pragma unroll
        for (int r = 0; r < 4; ++r)
          __hip_atomic_store(flg + r * 32 + j, t + 1, __ATOMIC_RELAXED,
                             __HIP_MEMORY_SCOPE_AGENT);
      }
      // out[] store after the flag (off the inter-block critical path)
      if (t >= LL && t < TT - LL) {
        float* op = out + ((size_t)l15 * (TT - 2 * LL) + (t - LL)) * 1024
                  + d * 512 + cb;
        *(f32x4*)op = h2v;
      }
      // gi for t+RD (fifo slot freed by A's consumed_s at step t)
      const int tg = t + RD;
      if (tg < TT) {
        const int tx = d ? (TT - 1 - tg) : tg;
        const unsigned short* Arow = Xb + (size_t)(tx * BB + l15) * FF + lk;
        int4v af[16];
#pragma unroll
        for (int kk = 0; kk < 16; ++kk)
          af[kk] = *(const int4v*)(Arow + kk * 32);
        f32x4 a0 = {0,0,0,0}, a1 = {0,0,0,0}, a2 = {0,0,0,0},
              a3 = {0,0,0,0}, a4 = {0,0,0,0}, a5 = {0,0,0,0};
#pragma unroll
        for (int kk = 0; kk < 16; kk += 2) {
          MFMA_WA(a0, wf[0][kk],     af[kk]);
          MFMA_WA(a2, wf[1][kk],     af[kk]);
          MFMA_WA(a4, wf[2][kk],     af[kk]);
          MFMA_WA(a1, wf[0][kk + 1], af[kk + 1]);
          MFMA_WA(a3, wf[1][kk + 1], af[kk + 1]);
          MFMA_WA(a5, wf[2][kk + 1], af[kk + 1]);
        }
        asm volatile("s_nop 7\n\ts_nop 7");
        while (tg - __hip_atomic_load(&consumed_s, __ATOMIC_ACQUIRE,
                                      __HIP_MEMORY_SCOPE_WORKGROUP) >= RD) {}
        const int2v xw = *(const int2v*)(Xb + (size_t)(tx * BB + l15) * FF + cb);
        const int gs = tg & (RD - 1);
#pragma unroll
        for (int jj = 0; jj < 4; ++jj) {
          const unsigned int xu = (jj < 2) ? (unsigned int)xw[0] : (unsigned int)xw[1];
          fifo[gs][lane][jj]      = a0[jj] + a1[jj] + bi0[jj];
          fifo[gs][lane][4 + jj]  = a2[jj] + a3[jj] + bi1[jj];
          fifo[gs][lane][8 + jj]  = a4[jj] + a5[jj] + bi2[jj];
          fifo[gs][lane][12 + jj] = bf2f((unsigned short)((jj & 1) ? (xu >> 16) : (xu & 0xffff)));
        }
        __hip_atomic_store(&wrote_s, tg + 1, __ATOMIC_RELEASE,
                           __HIP_MEMORY_SCOPE_WORKGROUP);
      }
    }
  }
}

// ---------------------------------------------------------------------------
extern "C" void kernel_launch(void* const* d_in, const int* in_sizes, int n_in,
                              void* d_out, int out_size, void* d_ws, size_t ws_size,
                              hipStream_t stream) {
  const float* x     = (const float*)d_in[0];
  const float* Wih_f = (const float*)d_in[1];
  const float* Whh_f = (const float*)d_in[2];
  const float* bih_f = (const float*)d_in[3];
  const float* bhh_f = (const float*)d_in[4];
  const float* Wih_b = (const float*)d_in[5];
  const float* Whh_b = (const float*)d_in[6];
  const float* bih_b = (const float*)d_in[7];
  const float* bhh_b = (const float*)d_in[8];
  float* out = (float*)d_out;

  char* ws = (char*)d_ws;
  unsigned short* Xb = (unsigned short*)ws;
  unsigned short* Hf = (unsigned short*)(ws + (size_t)33554432);
  unsigned short* Hb = (unsigned short*)(ws + (size_t)2 * 33554432);
  unsigned short* Wb = (unsigned short*)(ws + (size_t)3 * 33554432);
  int* flags         = (int*)(ws + (size_t)3 * 33554432 + 6291456);

  prep_x<<<65536, 256, 0, stream>>>(x, Xb);
  prep_w<<<12288, 256, 0, stream>>>(Whh_f, Wih_f, Whh_b, Wih_b, Wb);
  prep_flags<<<1, 256, 0, stream>>>(flags);
  bigru_rec<<<64, NTHR, 0, stream>>>(Xb, Hf, Hb, Wb, bih_f, bhh_f, bih_b, bhh_b,
                                     flags, out);
}